// Round 1
// baseline (3639.427 us; speedup 1.0000x reference)
//
#include <hip/hip_runtime.h>
#include <math.h>

// 2-layer LSTM (H=512), T=1024 teacher steps + 64 AR steps; only batch row 255
// reaches the output -> single-sequence LSTM. 64 persistent WGs, weights
// register-pinned via opaque asm.
//
// R6 restructure: PER-WAVE unit ownership. Wave rg of WG wg owns hidden unit
// U = wg*8+rg of BOTH layers (4 L1 rows + 4 L2 rows, 24 dot4/lane — same work
// and same 96 pinned weight floats/lane as before). After the in-wave
// butterfly reduce, lanes 0/1 gather the 4 gate pre-acts of unit U (4
// bpermutes), apply gates, and publish their two self-validating pairs
// immediately. This removes the pre[] LDS round trip, the second
// __syncthreads, and the wave-0 tail funnel that previously serialized every
// publish behind the slowest wave — all of which sat on the global critical
// path once per tick (1152 ticks).
//
// hvec is parity double-buffered (hvec[g&1]) so the only remaining barrier is
// the stage->read one inside poll_stage. Slot-reuse safety (inter-WG) is the
// same causality argument as before: a pair at gen g+1 implies its WG passed
// the tick-g barrier, hence all its gen g-1 comm reads completed. Intra-WG
// hvec reuse is safe because the per-tick barrier orders tick g reads before
// tick g+2 writes of the same parity buffer.
//
// Comm protocol unchanged: pair = (gen<<32 | bitcast(h)), relaxed agent-scope
// b64 atomics, line w pair i: i<8 -> h1 unit 8w+i, i>=8 -> h2 unit 8w+(i-8).
// In AR ticks every wave redundantly computes o = Wlin.h2 + blin (needed by
// its own lane 0 as the L1 x-input) via a 6-shuffle wave reduction.

#define G     64      // workgroups
#define NT    512     // threads/wg
#define HD    512     // hidden
#define TT    1024    // teacher steps
#define PRED  64      // prediction length
#define LINEF 64      // floats per comm line slot (256 B); pairs in words 0..31
#define SLOTF (G*LINEF)
#define STR   264     // hvec chunk stride in words (256 data + 8 pad banks)
#define AS    __HIP_MEMORY_SCOPE_AGENT

typedef unsigned long long u64;

#define LOG2E  1.44269504088896340736f

// opaque register pin: makes the asm the producer of the value so the
// compiler cannot rematerialize the original global load inside the loop
#define KEEP4(v) asm volatile("" : "+v"(v.x), "+v"(v.y), "+v"(v.z), "+v"(v.w))

__device__ __forceinline__ float sigf(float x){
  // 1/(1+exp(-x)) via v_exp_f32 + v_rcp_f32 (err ~1e-6, threshold 3.6e-4)
  return __builtin_amdgcn_rcpf(1.0f + __builtin_amdgcn_exp2f(-LOG2E * x));
}
__device__ __forceinline__ float tanhf_fast(float x){
  float e = __builtin_amdgcn_exp2f(2.0f * LOG2E * x);
  return 1.0f - 2.0f * __builtin_amdgcn_rcpf(e + 1.0f);
}
__device__ __forceinline__ float dot4(float4 a, float4 b){
  return a.x*b.x + a.y*b.y + a.z*b.z + a.w*b.w;
}

__global__ __launch_bounds__(NT, 1) void lstm2_kernel(
    const float* __restrict__ input,
    const float* __restrict__ Wih1, const float* __restrict__ Whh1,
    const float* __restrict__ bih1, const float* __restrict__ bhh1,
    const float* __restrict__ Wih2, const float* __restrict__ Whh2,
    const float* __restrict__ bih2, const float* __restrict__ bhh2,
    const float* __restrict__ Wlin, const float* __restrict__ blin,
    float* __restrict__ out, float* __restrict__ ws)
{
  // hvec chunk c (c=0..3) = words [c*STR, c*STR+256):
  //   c0: h1 units {8w..8w+3} of line w at word 4w   c1: h1 units {8w+4..8w+7}
  //   c2: h2 units {8w..8w+3}                        c3: h2 units {8w+4..8w+7}
  __shared__ __align__(16) float hvec[2][4*STR];   // parity double-buffered
  __shared__ __align__(16) float xrow[TT];

  float* comm = ws;             // [2][G][LINEF]

  const int t  = threadIdx.x;
  const int wg = blockIdx.x;
  const int rg = t >> 6;        // wave id 0..7
  const int sg = t & 63;        // lane
  const int U  = wg*8 + rg;     // hidden unit this wave owns (both layers)

  ((float2*)xrow)[t] = ((const float2*)(input + 255*TT))[t];

  // ---- weight preload: wave owns the 4 gate rows of unit U of both layers.
  // Row for gate q: R = q*HD + U. Lane sg covers cols [8sg, 8sg+8).
  float4 w1[4][2], w2x[4][2], w2h[4][2];
  #pragma unroll
  for (int q=0;q<4;q++){
    const int R = q*HD + U;
    const float* pa = Whh1 + R*HD + sg*8;
    w1[q][0]  = *(const float4*)(pa);
    w1[q][1]  = *(const float4*)(pa+4);
    const float* pb = Wih2 + R*HD + sg*8;
    w2x[q][0] = *(const float4*)(pb);
    w2x[q][1] = *(const float4*)(pb+4);
    const float* pc = Whh2 + R*HD + sg*8;
    w2h[q][0] = *(const float4*)(pc);
    w2h[q][1] = *(const float4*)(pc+4);
  }
  #pragma unroll
  for (int q=0;q<4;q++){
    KEEP4(w1[q][0]);  KEEP4(w1[q][1]);
    KEEP4(w2x[q][0]); KEEP4(w2x[q][1]);
    KEEP4(w2h[q][0]); KEEP4(w2h[q][1]);
  }

  // lane 0 computes L1 unit U, lane 1 computes L2 unit U
  float bias[4]={0,0,0,0}, wx[4]={0,0,0,0};
  if (sg < 2){
    const float* bi = sg ? bih2 : bih1;
    const float* bh = sg ? bhh2 : bhh1;
    #pragma unroll
    for (int q=0;q<4;q++){
      const int R = q*HD + U;
      bias[q] = bi[R] + bh[R];
      if (sg == 0) wx[q] = Wih1[R];
    }
  }
  float4 wl0 = *(const float4*)(Wlin + sg*8);
  float4 wl1 = *(const float4*)(Wlin + sg*8 + 4);
  const float blin0 = blin[0];

  float cst  = 0.f;     // persistent cell state (lane 0: c1_U, lane 1: c2_U)
  float hcur = 0.f;     // last h this lane produced (re-published every tick)

  // ---- consume tick g: all 512 threads. Lane t owns pairs {2j,2j+1} of line
  // w (w=t>>3, j=t&7). Spin until both pairs carry gen g; value is in-pair ->
  // single IC round-trip, no fence. Stage into hvec[g&1]; ONE barrier.
  auto poll_stage = [&](unsigned g){
    const int w = t >> 3, j = t & 7;
    const u64* dq = (const u64*)(comm + (g & 1u)*SLOTF + w*LINEF) + 2*j;
    u64 q0 = __hip_atomic_load(dq,     __ATOMIC_RELAXED, AS);
    u64 q1 = __hip_atomic_load(dq + 1, __ATOMIC_RELAXED, AS);
    while ((unsigned)(q0 >> 32) != g || (unsigned)(q1 >> 32) != g){
      q0 = __hip_atomic_load(dq,     __ATOMIC_RELAXED, AS);
      q1 = __hip_atomic_load(dq + 1, __ATOMIC_RELAXED, AS);
    }
    const int c  = j >> 1;
    const int wd = c*STR + 4*w + 2*(j & 1);
    float2 fv;
    fv.x = __builtin_bit_cast(float, (unsigned)q0);
    fv.y = __builtin_bit_cast(float, (unsigned)q1);
    *(float2*)(hvec[g & 1u] + wd) = fv;
    __syncthreads();
  };

  // ---- one tick of compute for this wave's unit U: dots + in-wave butterfly
  // reduce-scatter + lane-0/1 gate math + immediate per-wave publish.
  auto tick = [&](unsigned g, bool d1, bool d2, float xv){
    const float* hv = hvec[g & 1u];
    const float4 c0 = ((const float4*)(hv + 0*STR))[sg];
    const float4 c1 = ((const float4*)(hv + 1*STR))[sg];
    const float4 c2 = ((const float4*)(hv + 2*STR))[sg];
    const float4 c3 = ((const float4*)(hv + 3*STR))[sg];
    float v[8];   // v[0..3]=gates i,f,g,o of L1 unit U; v[4..7]=L2 unit U
    #pragma unroll
    for (int k=0;k<4;k++){
      v[k]   = dot4(w1[k][0],c0) + dot4(w1[k][1],c1);
      v[4+k] = dot4(w2x[k][0],c0) + dot4(w2x[k][1],c1)
             + dot4(w2h[k][0],c2) + dot4(w2h[k][1],c3);
    }
    // butterfly reduce-scatter: afterwards lane(j)=bitrev3(j) holds sum v[j]
    const int b0 = sg & 1, b1 = (sg>>1)&1, b2 = (sg>>2)&1;
    float k4[4];
    #pragma unroll
    for (int k=0;k<4;k++){
      float x = b0 ? v[k] : v[k+4];
      float y = __shfl_xor(x, 1, 64);
      k4[k] = (b0 ? v[k+4] : v[k]) + y;
    }
    float k2[2];
    #pragma unroll
    for (int k=0;k<2;k++){
      float x = b1 ? k4[k] : k4[k+2];
      float y = __shfl_xor(x, 2, 64);
      k2[k] = (b1 ? k4[k+2] : k4[k]) + y;
    }
    float k1;
    {
      float x = b2 ? k2[0] : k2[1];
      float y = __shfl_xor(x, 4, 64);
      k1 = (b2 ? k2[1] : k2[0]) + y;
    }
    k1 += __shfl_xor(k1, 8, 64);
    k1 += __shfl_xor(k1, 16, 64);
    k1 += __shfl_xor(k1, 32, 64);
    // gather gates of unit U for lane p (p=0: L1, p=1: L2).
    // value j lives at lane bitrev3(j): j={p,1+...}: i->lane p, f->4+p,
    // g->2+p, o->6+p.
    const int p = sg & 1;
    float pi = __shfl(k1, p,     64);
    float pf = __shfl(k1, 4 + p, 64);
    float pg = __shfl(k1, 2 + p, 64);
    float po = __shfl(k1, 6 + p, 64);
    const float xb = p ? 0.f : xv;
    pi += xb*wx[0] + bias[0];
    pf += xb*wx[1] + bias[1];
    pg += xb*wx[2] + bias[2];
    po += xb*wx[3] + bias[3];
    const bool act = p ? d2 : d1;       // lanes >=2 compute garbage, never read
    float cn = sigf(pf)*cst + sigf(pi)*tanhf_fast(pg);
    float hn = sigf(po)*tanhf_fast(cn);
    if (act){ cst = cn; hcur = hn; }
    if (sg < 2){
      u64 pr = ((u64)(g + 1u) << 32) | (u64)__builtin_bit_cast(unsigned, hcur);
      u64* nb = (u64*)(comm + ((g+1u) & 1u)*SLOTF + wg*LINEF);
      __hip_atomic_store(nb + rg + 8*sg, pr, __ATOMIC_RELAXED, AS);
    }
  };

  // o = Wlin . h2 + blin from hvec chunks 2/3; per-wave, result in ALL lanes
  auto computeO = [&](unsigned g)->float{
    const float* hv = hvec[g & 1u];
    float s = dot4(wl0, ((const float4*)(hv + 2*STR))[sg])
            + dot4(wl1, ((const float4*)(hv + 3*STR))[sg]);
    #pragma unroll
    for (int m=1;m<64;m<<=1) s += __shfl_xor(s, m, 64);
    return s + blin0;
  };

  __syncthreads();   // xrow staged

  unsigned g = 0;

  // ---- teacher: tick g computes L1 step g || L2 step g-1 ----
  for (int tk=0; tk<TT; ++tk, ++g){
    poll_stage(g);                       // hvec = [h1_{g-1} | h2_{g-2}]
    tick(g, true, tk >= 1, xrow[tk]);    // publish [h1_g | h2_{g-1}] pairs
  }

  // ---- drain: L2 step 1023 ----
  poll_stage(g);                         // [h1_1023 | h2_1022]
  tick(g, false, true, 0.f);             // publish [h1_1023 | h2_1023]
  ++g;

  // ---- AR: steps s = 1024..1086, 2 ticks each ----
  for (int s=TT; s<TT+PRED-1; ++s){
    poll_stage(g);                       // [h1_{s-1} | h2_{s-1}]
    float xv = computeO(g);              // o_{s-1}, all waves redundantly
    if (wg == 0 && t == 0) out[s - TT] = xv;
    tick(g, true, false, xv);            // publish [h1_s | h2_{s-1}]
    ++g;

    poll_stage(g);                       // [h1_s | h2_{s-1}]
    tick(g, false, true, 0.f);           // publish [h1_s | h2_s]
    ++g;
  }

  // ---- final output o_1086 ----
  poll_stage(g);                         // [h1_1086 | h2_1086]
  float xv = computeO(g);
  if (wg == 0 && t == 0) out[PRED - 1] = xv;
}

extern "C" void kernel_launch(void* const* d_in, const int* in_sizes, int n_in,
                              void* d_out, int out_size, void* d_ws, size_t ws_size,
                              hipStream_t stream) {
  const float* input = (const float*)d_in[0];
  // d_in[1] = pred_len (fixed 64, baked in)
  const float* Wih1 = (const float*)d_in[2];
  const float* Whh1 = (const float*)d_in[3];
  const float* bih1 = (const float*)d_in[4];
  const float* bhh1 = (const float*)d_in[5];
  const float* Wih2 = (const float*)d_in[6];
  const float* Whh2 = (const float*)d_in[7];
  const float* bih2 = (const float*)d_in[8];
  const float* bhh2 = (const float*)d_in[9];
  const float* Wlin = (const float*)d_in[10];
  const float* blin = (const float*)d_in[11];

  // zero comm: u64 zero pairs == (gen 0, h=0.0f) -> valid initial state
  hipMemsetAsync(d_ws, 0, 2 * SLOTF * sizeof(float), stream);

  lstm2_kernel<<<dim3(G), dim3(NT), 0, stream>>>(
      input, Wih1, Whh1, bih1, bhh1, Wih2, Whh2, bih2, bhh2, Wlin, blin,
      (float*)d_out, (float*)d_ws);
}

// Round 2
// 2079.980 us; speedup vs baseline: 1.7497x; 1.7497x over previous
//
#include <hip/hip_runtime.h>
#include <math.h>

// 2-layer LSTM (H=512), T=1024 teacher steps + 64 AR steps; only batch row 255
// reaches the output -> single-sequence LSTM. 64 persistent WGs, weights
// register-pinned via opaque asm (VGPR_Count=88 proved re-load otherwise).
//
// R7 = R5 comm protocol + R6 per-wave gate math:
//  * Publish is ONE coalesced 128B store from wave 0 (16 lanes x 8B pairs).
//    R6 proved scattered per-wave 8B publishes are catastrophic (4x WRITE_SIZE,
//    2x FETCH, 2x dur, livelock outlier): a line must become visible in one
//    IC transaction so consumers detect in a single round trip.
//  * Gate math is per-wave (wave rg owns unit U=wg*8+rg of BOTH layers),
//    computed BEFORE the handoff barrier on lanes 0/1 of each wave, in
//    parallel across waves. Wave 0's post-barrier critical path is only:
//    16-float LDS read -> pack -> coalesced store (~80cy), replacing R5's
//    serial 4-shuffle gather + sigmoid/tanh chain (~250cy) that sat on the
//    global critical path once per tick (1152 ticks).
//
// Comm protocol (R5, proven): pair = (gen<<32 | bitcast(h)) as relaxed
// agent-scope b64 atomics; a WG's line is 16 pairs = 128B. Consumers: all 512
// threads spin on b64 atomic loads (lane t owns pairs {2j,2j+1} of line t>>3)
// until gen fields == g -> detection and data in ONE IC round trip. 8B
// atomicity forbids torn reads; slot-reuse safe by value-dependency causality.
// Two barriers/tick: stage->read (poll_stage) and hout handoff (tick), so the
// single hvec buffer is safe (reads of tick g complete before bar2; next
// tick's staging writes happen after bar2).
// hvec chunk stride padded 256->264 words (4-way staging conflicts otherwise).

#define G     64      // workgroups
#define NT    512     // threads/wg
#define HD    512     // hidden
#define TT    1024    // teacher steps
#define PRED  64      // prediction length
#define LINEF 64      // floats per comm line slot (256 B); pairs in words 0..31
#define SLOTF (G*LINEF)
#define STR   264     // hvec chunk stride in words (256 data + 8 pad banks)
#define AS    __HIP_MEMORY_SCOPE_AGENT

typedef unsigned long long u64;

#define LOG2E  1.44269504088896340736f

// opaque register pin: makes the asm the producer of the value so the
// compiler cannot rematerialize the original global load inside the loop
#define KEEP4(v) asm volatile("" : "+v"(v.x), "+v"(v.y), "+v"(v.z), "+v"(v.w))

__device__ __forceinline__ float sigf(float x){
  // 1/(1+exp(-x)) via v_exp_f32 + v_rcp_f32 (err ~1e-6, threshold 3.6e-4)
  return __builtin_amdgcn_rcpf(1.0f + __builtin_amdgcn_exp2f(-LOG2E * x));
}
__device__ __forceinline__ float tanhf_fast(float x){
  float e = __builtin_amdgcn_exp2f(2.0f * LOG2E * x);
  return 1.0f - 2.0f * __builtin_amdgcn_rcpf(e + 1.0f);
}
__device__ __forceinline__ float dot4(float4 a, float4 b){
  return a.x*b.x + a.y*b.y + a.z*b.z + a.w*b.w;
}

__global__ __launch_bounds__(NT, 1) void lstm2_kernel(
    const float* __restrict__ input,
    const float* __restrict__ Wih1, const float* __restrict__ Whh1,
    const float* __restrict__ bih1, const float* __restrict__ bhh1,
    const float* __restrict__ Wih2, const float* __restrict__ Whh2,
    const float* __restrict__ bih2, const float* __restrict__ bhh2,
    const float* __restrict__ Wlin, const float* __restrict__ blin,
    float* __restrict__ out, float* __restrict__ ws)
{
  // hvec chunk c (c=0..3) = words [c*STR, c*STR+256):
  //   c0: h1 units {8w..8w+3} of line w at word 4w   c1: h1 units {8w+4..8w+7}
  //   c2: h2 units {8w..8w+3}                        c3: h2 units {8w+4..8w+7}
  __shared__ __align__(16) float hvec[4*STR];
  __shared__ __align__(16) float xrow[TT];
  __shared__ float hout[16];    // per-wave gate results: [rg]=h1_U, [8+rg]=h2_U

  float* comm = ws;             // [2][G][LINEF]

  const int t  = threadIdx.x;
  const int wg = blockIdx.x;
  const int rg = t >> 6;        // wave id 0..7
  const int sg = t & 63;        // lane
  const int U  = wg*8 + rg;     // hidden unit this wave owns (both layers)

  ((float2*)xrow)[t] = ((const float2*)(input + 255*TT))[t];

  // ---- weight preload: wave owns the 4 gate rows of unit U of both layers.
  // Row for gate q: R = q*HD + U. Lane sg covers cols [8sg, 8sg+8).
  float4 w1[4][2], w2x[4][2], w2h[4][2];
  #pragma unroll
  for (int q=0;q<4;q++){
    const int R = q*HD + U;
    const float* pa = Whh1 + R*HD + sg*8;
    w1[q][0]  = *(const float4*)(pa);
    w1[q][1]  = *(const float4*)(pa+4);
    const float* pb = Wih2 + R*HD + sg*8;
    w2x[q][0] = *(const float4*)(pb);
    w2x[q][1] = *(const float4*)(pb+4);
    const float* pc = Whh2 + R*HD + sg*8;
    w2h[q][0] = *(const float4*)(pc);
    w2h[q][1] = *(const float4*)(pc+4);
  }
  #pragma unroll
  for (int q=0;q<4;q++){
    KEEP4(w1[q][0]);  KEEP4(w1[q][1]);
    KEEP4(w2x[q][0]); KEEP4(w2x[q][1]);
    KEEP4(w2h[q][0]); KEEP4(w2h[q][1]);
  }

  // lane 0 computes L1 unit U, lane 1 computes L2 unit U
  float bias[4]={0,0,0,0}, wx[4]={0,0,0,0};
  if (sg < 2){
    const float* bi = sg ? bih2 : bih1;
    const float* bh = sg ? bhh2 : bhh1;
    #pragma unroll
    for (int q=0;q<4;q++){
      const int R = q*HD + U;
      bias[q] = bi[R] + bh[R];
      if (sg == 0) wx[q] = Wih1[R];
    }
  }
  float4 wl0 = *(const float4*)(Wlin + sg*8);
  float4 wl1 = *(const float4*)(Wlin + sg*8 + 4);
  const float blin0 = blin[0];

  float cst  = 0.f;     // persistent cell state (lane 0: c1_U, lane 1: c2_U)
  float hcur = 0.f;     // last h this lane produced (re-published every tick)

  // ---- consume tick g: all 512 threads. Lane t owns pairs {2j,2j+1} of line
  // w (w=t>>3, j=t&7). Spin until both pairs carry gen g; value is in-pair ->
  // single IC round-trip, no fence. Stage into hvec; barrier 1.
  auto poll_stage = [&](unsigned g){
    const int w = t >> 3, j = t & 7;
    const u64* dq = (const u64*)(comm + (g & 1u)*SLOTF + w*LINEF) + 2*j;
    u64 q0, q1;
    do {
      q0 = __hip_atomic_load(dq,     __ATOMIC_RELAXED, AS);
      q1 = __hip_atomic_load(dq + 1, __ATOMIC_RELAXED, AS);
    } while ((unsigned)(q0 >> 32) != g || (unsigned)(q1 >> 32) != g);
    const int c  = j >> 1;
    const int wd = c*STR + 4*w + 2*(j & 1);
    float2 fv;
    fv.x = __builtin_bit_cast(float, (unsigned)q0);
    fv.y = __builtin_bit_cast(float, (unsigned)q1);
    *(float2*)(hvec + wd) = fv;
    __syncthreads();
  };

  // ---- one tick: per-wave dots + butterfly + lane-0/1 gate math (parallel
  // across waves, BEFORE the barrier) -> LDS handoff -> wave 0 publishes the
  // whole line as one coalesced 128B store (minimal post-barrier path).
  auto tick = [&](unsigned g, bool d1, bool d2, float xv){
    const float4 c0 = ((const float4*)(hvec + 0*STR))[sg];
    const float4 c1 = ((const float4*)(hvec + 1*STR))[sg];
    const float4 c2 = ((const float4*)(hvec + 2*STR))[sg];
    const float4 c3 = ((const float4*)(hvec + 3*STR))[sg];
    float v[8];   // v[0..3]=gates i,f,g,o of L1 unit U; v[4..7]=L2 unit U
    #pragma unroll
    for (int k=0;k<4;k++){
      v[k]   = dot4(w1[k][0],c0) + dot4(w1[k][1],c1);
      v[4+k] = dot4(w2x[k][0],c0) + dot4(w2x[k][1],c1)
             + dot4(w2h[k][0],c2) + dot4(w2h[k][1],c3);
    }
    // butterfly reduce-scatter: afterwards lane(j)=bitrev3(j) holds sum v[j]
    const int b0 = sg & 1, b1 = (sg>>1)&1, b2 = (sg>>2)&1;
    float k4[4];
    #pragma unroll
    for (int k=0;k<4;k++){
      float x = b0 ? v[k] : v[k+4];
      float y = __shfl_xor(x, 1, 64);
      k4[k] = (b0 ? v[k+4] : v[k]) + y;
    }
    float k2[2];
    #pragma unroll
    for (int k=0;k<2;k++){
      float x = b1 ? k4[k] : k4[k+2];
      float y = __shfl_xor(x, 2, 64);
      k2[k] = (b1 ? k4[k+2] : k4[k]) + y;
    }
    float k1;
    {
      float x = b2 ? k2[0] : k2[1];
      float y = __shfl_xor(x, 4, 64);
      k1 = (b2 ? k2[1] : k2[0]) + y;
    }
    k1 += __shfl_xor(k1, 8, 64);
    k1 += __shfl_xor(k1, 16, 64);
    k1 += __shfl_xor(k1, 32, 64);
    // gather gates of unit U for lane p (p=0: L1, p=1: L2).
    // value j lives at lane bitrev3(j): i->lane p, f->4+p, g->2+p, o->6+p.
    const int p = sg & 1;
    float pi = __shfl(k1, p,     64);
    float pf = __shfl(k1, 4 + p, 64);
    float pg = __shfl(k1, 2 + p, 64);
    float po = __shfl(k1, 6 + p, 64);
    const float xb = p ? 0.f : xv;
    pi += xb*wx[0] + bias[0];
    pf += xb*wx[1] + bias[1];
    pg += xb*wx[2] + bias[2];
    po += xb*wx[3] + bias[3];
    const bool act = p ? d2 : d1;       // lanes >=2 compute garbage, never read
    float cn = sigf(pf)*cst + sigf(pi)*tanhf_fast(pg);
    float hn = sigf(po)*tanhf_fast(cn);
    if (act){ cst = cn; hcur = hn; }
    if (sg < 2) hout[rg + 8*sg] = hcur;   // [rg]=h1_U, [8+rg]=h2_U
    __syncthreads();                      // barrier 2: handoff + hvec-reuse
    if (t < 16){
      u64 pr = ((u64)(g + 1u) << 32)
             | (u64)__builtin_bit_cast(unsigned, hout[t]);
      u64* nb = (u64*)(comm + ((g+1u) & 1u)*SLOTF + wg*LINEF);
      __hip_atomic_store(nb + t, pr, __ATOMIC_RELAXED, AS);
    }
  };

  // o = Wlin . h2 + blin from hvec chunks 2/3; per-wave, result in ALL lanes
  auto computeO = [&](){
    float s = dot4(wl0, ((const float4*)(hvec + 2*STR))[sg])
            + dot4(wl1, ((const float4*)(hvec + 3*STR))[sg]);
    #pragma unroll
    for (int m=1;m<64;m<<=1) s += __shfl_xor(s, m, 64);
    return s + blin0;
  };

  __syncthreads();   // xrow staged

  unsigned g = 0;

  // ---- teacher: tick g computes L1 step g || L2 step g-1 ----
  for (int tk=0; tk<TT; ++tk, ++g){
    poll_stage(g);                       // hvec = [h1_{g-1} | h2_{g-2}]
    tick(g, true, tk >= 1, xrow[tk]);    // publish [h1_g | h2_{g-1}] pairs
  }

  // ---- drain: L2 step 1023 ----
  poll_stage(g);                         // [h1_1023 | h2_1022]
  tick(g, false, true, 0.f);             // publish [h1_1023 | h2_1023]
  ++g;

  // ---- AR: steps s = 1024..1086, 2 ticks each ----
  for (int s=TT; s<TT+PRED-1; ++s){
    poll_stage(g);                       // [h1_{s-1} | h2_{s-1}]
    float xv = computeO();               // o_{s-1}, all waves redundantly
    if (wg == 0 && t == 0) out[s - TT] = xv;
    tick(g, true, false, xv);            // publish [h1_s | h2_{s-1}]
    ++g;

    poll_stage(g);                       // [h1_s | h2_{s-1}]
    tick(g, false, true, 0.f);           // publish [h1_s | h2_s]
    ++g;
  }

  // ---- final output o_1086 ----
  poll_stage(g);                         // [h1_1086 | h2_1086]
  float xv = computeO();
  if (wg == 0 && t == 0) out[PRED - 1] = xv;
}

extern "C" void kernel_launch(void* const* d_in, const int* in_sizes, int n_in,
                              void* d_out, int out_size, void* d_ws, size_t ws_size,
                              hipStream_t stream) {
  const float* input = (const float*)d_in[0];
  // d_in[1] = pred_len (fixed 64, baked in)
  const float* Wih1 = (const float*)d_in[2];
  const float* Whh1 = (const float*)d_in[3];
  const float* bih1 = (const float*)d_in[4];
  const float* bhh1 = (const float*)d_in[5];
  const float* Wih2 = (const float*)d_in[6];
  const float* Whh2 = (const float*)d_in[7];
  const float* bih2 = (const float*)d_in[8];
  const float* bhh2 = (const float*)d_in[9];
  const float* Wlin = (const float*)d_in[10];
  const float* blin = (const float*)d_in[11];

  // zero comm: u64 zero pairs == (gen 0, h=0.0f) -> valid initial state
  hipMemsetAsync(d_ws, 0, 2 * SLOTF * sizeof(float), stream);

  lstm2_kernel<<<dim3(G), dim3(NT), 0, stream>>>(
      input, Wih1, Whh1, bih1, bhh1, Wih2, Whh2, bih2, bhh2, Wlin, blin,
      (float*)d_out, (float*)d_ws);
}